// Round 1
// baseline (872.234 us; speedup 1.0000x reference)
//
#include <hip/hip_runtime.h>
#include <hip/hip_bf16.h>

typedef __bf16 bf16_t;
typedef __bf16 bf16x8_t __attribute__((ext_vector_type(8)));
typedef __bf16 bf16x4_t __attribute__((ext_vector_type(4)));
typedef float f32x4_t __attribute__((ext_vector_type(4)));

#define EPI_SCALE 0
#define EPI_RES_BF16 1
#define EPI_RELU_RES 2
#define EPI_BIAS 3

// ---------------------------------------------------------------------------
// Tiled bf16 MFMA GEMM, B given TRANSPOSED (Bt is [N][K] row-major).
// C[M,N] = epilogue(A[M,K] @ Bt^T * alpha).
// Block = 256 threads = 4 waves (2x2), tile 128x128, BK=32.
// Fragment loads: 8 contiguous bf16 per lane for BOTH A and B -> the k
// permutation cancels between operands (only C/D layout must be exact).
// ---------------------------------------------------------------------------
template <int EPI>
__global__ __launch_bounds__(256) void gemm_bt(
    const bf16_t* __restrict__ A, long aBatch, int lda,
    const bf16_t* __restrict__ Bt, long bBatch, int ldb,
    float* __restrict__ Cf, long cfBatch, int ldc,
    bf16_t* __restrict__ Cb, long cbBatch,
    const float* __restrict__ Res, long resBatch,
    const float* __restrict__ bias,
    float alpha, int K)
{
  const int bz = blockIdx.z;
  A += (long)bz * aBatch;
  Bt += (long)bz * bBatch;
  Cf += (long)bz * cfBatch;
  if (Cb) Cb += (long)bz * cbBatch;
  if (Res) Res += (long)bz * resBatch;

  __shared__ bf16_t shA[128 * 40];  // 32 bf16 per row + 8 pad (2-way bank alias only)
  __shared__ bf16_t shB[128 * 40];

  const int tid = threadIdx.x;
  const int wave = tid >> 6, lane = tid & 63;
  const int wm = wave >> 1, wn = wave & 1;
  const int lr = lane & 15, lh = lane >> 4;

  const bf16_t* Ab = A + (long)(blockIdx.y * 128) * lda;
  const bf16_t* Bb = Bt + (long)(blockIdx.x * 128) * ldb;

  f32x4_t acc[4][4] = {};

  const int r0 = tid >> 2;            // staging row (chunk 0): 0..63
  const int cc = (tid & 3) << 3;      // staging k-offset in elems: 0,8,16,24

  const int nk = K >> 5;
  for (int kt = 0; kt < nk; ++kt) {
    const int k0 = kt << 5;
    // ---- stage A/B tiles (128 x 32 bf16 each) via registers ----
    {
      int r = r0;
      *(int4*)(shA + r * 40 + cc) = *(const int4*)(Ab + (long)r * lda + k0 + cc);
      *(int4*)(shB + r * 40 + cc) = *(const int4*)(Bb + (long)r * ldb + k0 + cc);
      r += 64;
      *(int4*)(shA + r * 40 + cc) = *(const int4*)(Ab + (long)r * lda + k0 + cc);
      *(int4*)(shB + r * 40 + cc) = *(const int4*)(Bb + (long)r * ldb + k0 + cc);
    }
    __syncthreads();
    // ---- fragments + 16 MFMAs ----
    bf16x8_t af[4], bfr[4];
#pragma unroll
    for (int m = 0; m < 4; ++m)
      af[m] = *(const bf16x8_t*)(shA + (wm * 64 + m * 16 + lr) * 40 + lh * 8);
#pragma unroll
    for (int n = 0; n < 4; ++n)
      bfr[n] = *(const bf16x8_t*)(shB + (wn * 64 + n * 16 + lr) * 40 + lh * 8);
#pragma unroll
    for (int m = 0; m < 4; ++m)
#pragma unroll
      for (int n = 0; n < 4; ++n)
        acc[m][n] = __builtin_amdgcn_mfma_f32_16x16x32_bf16(af[m], bfr[n], acc[m][n], 0, 0, 0);
    __syncthreads();
  }

  // ---- epilogue: C/D layout col = lane&15, row = (lane>>4)*4 + reg ----
  const long gr0 = (long)blockIdx.y * 128 + wm * 64;
  const int gc0 = blockIdx.x * 128 + wn * 64;
#pragma unroll
  for (int m = 0; m < 4; ++m) {
#pragma unroll
    for (int n = 0; n < 4; ++n) {
#pragma unroll
      for (int r = 0; r < 4; ++r) {
        const long row = gr0 + m * 16 + lh * 4 + r;
        const int col = gc0 + n * 16 + lr;
        const float v = acc[m][n][r];
        if constexpr (EPI == EPI_SCALE) {
          Cf[row * ldc + col] = v * alpha;
        } else if constexpr (EPI == EPI_BIAS) {
          Cf[row * ldc + col] = v + bias[col];
        } else if constexpr (EPI == EPI_RES_BF16) {
          const float o = Res[row * ldc + col] + v;
          Cf[row * ldc + col] = o;
          Cb[row * ldc + col] = (bf16_t)o;
        } else {  // EPI_RELU_RES
          float t = v + bias[col];
          t = t > 0.f ? t : 0.f;
          const float o = Res[row * ldc + col] + t;
          Cf[row * ldc + col] = o;
          Cb[row * ldc + col] = (bf16_t)o;
        }
      }
    }
  }
}

// ---------------------------------------------------------------------------
// Row softmax over S f32 values, in-place bf16 writeback (rows at f32 stride,
// so P is later read with lda = 2*S bf16 elems). One block (256 thr) per row.
// All f32 reads happen before the first barrier; bf16 writes after the second.
// ---------------------------------------------------------------------------
__global__ __launch_bounds__(256) void softmax_rows(float* __restrict__ scores, int S)
{
  const long row = blockIdx.x;
  float* p = scores + row * (long)S;
  const int t = threadIdx.x;
  const int lane = t & 63, wave = t >> 6;

  float4 v0 = ((const float4*)p)[t * 2];
  float4 v1 = ((const float4*)p)[t * 2 + 1];
  float e[8] = {v0.x, v0.y, v0.z, v0.w, v1.x, v1.y, v1.z, v1.w};

  float m = e[0];
#pragma unroll
  for (int j = 1; j < 8; ++j) m = fmaxf(m, e[j]);
#pragma unroll
  for (int off = 32; off >= 1; off >>= 1) m = fmaxf(m, __shfl_xor(m, off));

  __shared__ float redm[4], reds[4];
  if (lane == 0) redm[wave] = m;
  __syncthreads();
  m = fmaxf(fmaxf(redm[0], redm[1]), fmaxf(redm[2], redm[3]));

  float s = 0.f;
#pragma unroll
  for (int j = 0; j < 8; ++j) { e[j] = __expf(e[j] - m); s += e[j]; }
#pragma unroll
  for (int off = 32; off >= 1; off >>= 1) s += __shfl_xor(s, off);
  if (lane == 0) reds[wave] = s;
  __syncthreads();
  s = reds[0] + reds[1] + reds[2] + reds[3];
  const float inv = 1.f / s;

  bf16x8_t ob;
#pragma unroll
  for (int j = 0; j < 8; ++j) ob[j] = (bf16_t)(e[j] * inv);
  ((bf16x8_t*)p)[t] = ob;
}

// ---------------------------------------------------------------------------
// f32 copy + bf16 cast (x -> xf, xb)
// ---------------------------------------------------------------------------
__global__ void cast_copy(const float* __restrict__ in, float* __restrict__ outf,
                          bf16_t* __restrict__ outb, long n4)
{
  long i = (long)blockIdx.x * blockDim.x + threadIdx.x;
  const long stride = (long)gridDim.x * blockDim.x;
  for (; i < n4; i += stride) {
    float4 v = ((const float4*)in)[i];
    ((float4*)outf)[i] = v;
    bf16x4_t bv;
    bv[0] = (bf16_t)v.x; bv[1] = (bf16_t)v.y; bv[2] = (bf16_t)v.z; bv[3] = (bf16_t)v.w;
    ((bf16x4_t*)outb)[i] = bv;
  }
}

// ---------------------------------------------------------------------------
// Batched f32 [R][C] -> bf16 [C][R] transpose-cast, 32x32 LDS tile
// ---------------------------------------------------------------------------
__global__ void transpose_cast(const float* __restrict__ in, long inBatch, int R, int C,
                               bf16_t* __restrict__ out, long outBatch)
{
  __shared__ float tile[32][33];
  const float* src = in + (long)blockIdx.z * inBatch;
  bf16_t* dst = out + (long)blockIdx.z * outBatch;
  const int c0 = blockIdx.x * 32, r0 = blockIdx.y * 32;
  const int tx = threadIdx.x, ty = threadIdx.y;
#pragma unroll
  for (int i = 0; i < 32; i += 8) tile[ty + i][tx] = src[(long)(r0 + ty + i) * C + (c0 + tx)];
  __syncthreads();
#pragma unroll
  for (int i = 0; i < 32; i += 8)
    dst[(long)(c0 + ty + i) * R + (r0 + tx)] = (bf16_t)tile[tx][ty + i];
}

// ---------------------------------------------------------------------------
extern "C" void kernel_launch(void* const* d_in, const int* in_sizes, int n_in,
                              void* d_out, int out_size, void* d_ws, size_t ws_size,
                              hipStream_t stream)
{
  constexpr int L = 4, NB = 4, S = 2048, D = 1024;
  const float* x  = (const float*)d_in[0];
  const float* W  = (const float*)d_in[1];
  const float* bv = (const float*)d_in[2];
  const float* Wo = (const float*)d_in[3];
  const float* bo = (const float*)d_in[4];

  // workspace layout (~186 MB)
  char* ws = (char*)d_ws;
  size_t off = 0;
  float* scores = (float*)(ws + off); off += (size_t)NB * S * S * 4;   // 67 MB
  float* xf = (float*)(ws + off); off += (size_t)NB * S * D * 4;       // 33.5 MB
  float* yf = (float*)(ws + off); off += (size_t)NB * S * D * 4;       // 33.5 MB
  bf16_t* xb  = (bf16_t*)(ws + off); off += (size_t)NB * S * D * 2;    // 16.7 MB
  bf16_t* xbT = (bf16_t*)(ws + off); off += (size_t)NB * S * D * 2;    // 16.7 MB
  bf16_t* yb  = (bf16_t*)(ws + off); off += (size_t)NB * S * D * 2;    // 16.7 MB
  bf16_t* WbT  = (bf16_t*)(ws + off); off += (size_t)L * D * D * 2;    // 8.4 MB
  bf16_t* WobT = (bf16_t*)(ws + off); off += (size_t)D * D * 2;        // 2 MB

  const long n4 = (long)NB * S * D / 4;
  cast_copy<<<2048, 256, 0, stream>>>(x, xf, xb, n4);
  transpose_cast<<<dim3(D / 32, S / 32, NB), dim3(32, 8), 0, stream>>>(
      x, (long)S * D, S, D, xbT, (long)D * S);
  transpose_cast<<<dim3(D / 32, D / 32, L), dim3(32, 8), 0, stream>>>(
      W, (long)D * D, D, D, WbT, (long)D * D);
  transpose_cast<<<dim3(D / 32, D / 32, 1), dim3(32, 8), 0, stream>>>(
      Wo, 0, D, D, WobT, 0);

  const float inv_sqrt_d = 0.03125f;  // 1/sqrt(1024)

  for (int i = 0; i < L; ++i) {
    // scores = xb @ xb^T * inv_sqrt_d  (Bt-layout is x itself)
    gemm_bt<EPI_SCALE><<<dim3(S / 128, S / 128, NB), 256, 0, stream>>>(
        xb, (long)S * D, D, xb, (long)S * D, D,
        scores, (long)S * S, S, nullptr, 0, nullptr, 0, nullptr,
        inv_sqrt_d, D);
    // softmax rows, in-place bf16 P (lda = 2*S)
    softmax_rows<<<NB * S, 256, 0, stream>>>(scores, S);
    // y = xf + P @ x   (Bt = xbT)
    gemm_bt<EPI_RES_BF16><<<dim3(D / 128, S / 128, NB), 256, 0, stream>>>(
        (const bf16_t*)scores, (long)2 * S * S, 2 * S, xbT, (long)D * S, S,
        yf, (long)S * D, D, yb, (long)S * D, xf, (long)S * D, nullptr,
        1.0f, S);
    // z = yf + relu(yb @ W[i] + b[i])  -> xf, xb   (batch-flattened M = NB*S)
    gemm_bt<EPI_RELU_RES><<<dim3(D / 128, (NB * S) / 128, 1), 256, 0, stream>>>(
        yb, 0, D, WbT + (size_t)i * D * D, 0, D,
        xf, 0, D, xb, 0, yf, 0, bv + (size_t)i * D,
        1.0f, D);
    if (i < L - 1)
      transpose_cast<<<dim3(D / 32, S / 32, NB), dim3(32, 8), 0, stream>>>(
          xf, (long)S * D, S, D, xbT, (long)D * S);
  }

  // out = xb @ Wo + bo
  gemm_bt<EPI_BIAS><<<dim3(D / 128, (NB * S) / 128, 1), 256, 0, stream>>>(
      xb, 0, D, WobT, 0, D,
      (float*)d_out, 0, D, nullptr, 0, nullptr, 0, bo,
      1.0f, D);
}

// Round 2
// 826.717 us; speedup vs baseline: 1.0551x; 1.0551x over previous
//
#include <hip/hip_runtime.h>
#include <hip/hip_bf16.h>

typedef __bf16 bf16_t;
typedef __bf16 bf16x8_t __attribute__((ext_vector_type(8)));
typedef __bf16 bf16x4_t __attribute__((ext_vector_type(4)));
typedef float f32x4_t __attribute__((ext_vector_type(4)));

#define EPI_SCALE 0
#define EPI_RES_BF16 1
#define EPI_RELU_RES 2
#define EPI_BIAS 3

// async 16B global -> LDS (gfx950 global_load_lds_dwordx4)
__device__ __forceinline__ void gload_lds16(const bf16_t* g, bf16_t* l) {
  __builtin_amdgcn_global_load_lds(
      (const __attribute__((address_space(1))) void*)g,
      (__attribute__((address_space(3))) void*)l, 16, 0, 0);
}

// ---------------------------------------------------------------------------
// Tiled bf16 MFMA GEMM (m97 structure), B given TRANSPOSED (Bt is [N][K]).
// C[M,N] = epilogue(A[M,K] @ Bt^T * alpha).
// Block = 256 threads = 4 waves (2x2), tile 128x128, BK=32.
// Staging: global_load_lds width=16, LINEAR LDS tiles (128x32, no pad).
// ---------------------------------------------------------------------------
template <int EPI>
__global__ __launch_bounds__(256) void gemm_bt(
    const bf16_t* __restrict__ A, long aBatch, int lda,
    const bf16_t* __restrict__ Bt, long bBatch, int ldb,
    float* __restrict__ Cf, long cfBatch, int ldc,
    bf16_t* __restrict__ Cb, long cbBatch,
    const float* __restrict__ Res, long resBatch,
    const float* __restrict__ bias,
    float alpha, int K)
{
  const int bz = blockIdx.z;
  A += (long)bz * aBatch;
  Bt += (long)bz * bBatch;
  Cf += (long)bz * cfBatch;
  if (Cb) Cb += (long)bz * cbBatch;
  if (Res) Res += (long)bz * resBatch;

  __shared__ bf16_t shA[128 * 32];  // linear: global_load_lds writes base+lane*16B
  __shared__ bf16_t shB[128 * 32];

  const int tid = threadIdx.x;
  const int wave = tid >> 6, lane = tid & 63;
  const int wm = wave >> 1, wn = wave & 1;
  const int lr = lane & 15, lh = lane >> 4;

  // staging geometry: wave w, issue j covers rows w*16 + j*64 .. +15
  const int srow = wave * 16 + (lane >> 2);  // + j*64
  const int scol = (lane & 3) << 3;          // 0,8,16,24 elems
  const bf16_t* Ag = A + (long)(blockIdx.y * 128 + srow) * lda + scol;
  const bf16_t* Bg = Bt + (long)(blockIdx.x * 128 + srow) * ldb + scol;
  bf16_t* const lA = shA + wave * 16 * 32;   // wave-uniform dest, +j*64*32
  bf16_t* const lB = shB + wave * 16 * 32;

  f32x4_t acc[4][4] = {};

  const int nk = K >> 5;
  for (int kt = 0; kt < nk; ++kt) {
    const long k0 = (long)kt << 5;
    gload_lds16(Ag + k0, lA);
    gload_lds16(Ag + 64 * lda + k0, lA + 64 * 32);
    gload_lds16(Bg + k0, lB);
    gload_lds16(Bg + 64 * ldb + k0, lB + 64 * 32);
    __syncthreads();  // drains vmcnt -> staged data visible

    bf16x8_t af[4], bfr[4];
#pragma unroll
    for (int m = 0; m < 4; ++m)
      af[m] = *(const bf16x8_t*)(shA + (wm * 64 + m * 16 + lr) * 32 + lh * 8);
#pragma unroll
    for (int n = 0; n < 4; ++n)
      bfr[n] = *(const bf16x8_t*)(shB + (wn * 64 + n * 16 + lr) * 32 + lh * 8);
#pragma unroll
    for (int m = 0; m < 4; ++m)
#pragma unroll
      for (int n = 0; n < 4; ++n)
        acc[m][n] = __builtin_amdgcn_mfma_f32_16x16x32_bf16(af[m], bfr[n], acc[m][n], 0, 0, 0);
    __syncthreads();  // all waves done reading before next stage overwrites
  }

  // ---- epilogue: C/D layout col = lane&15, row = (lane>>4)*4 + reg ----
  const long gr0 = (long)blockIdx.y * 128 + wm * 64;
  const int gc0 = blockIdx.x * 128 + wn * 64;
#pragma unroll
  for (int m = 0; m < 4; ++m) {
#pragma unroll
    for (int n = 0; n < 4; ++n) {
#pragma unroll
      for (int r = 0; r < 4; ++r) {
        const long row = gr0 + m * 16 + lh * 4 + r;
        const int col = gc0 + n * 16 + lr;
        const float v = acc[m][n][r];
        if constexpr (EPI == EPI_SCALE) {
          Cf[row * ldc + col] = v * alpha;
        } else if constexpr (EPI == EPI_BIAS) {
          Cf[row * ldc + col] = v + bias[col];
        } else if constexpr (EPI == EPI_RES_BF16) {
          const float o = Res[row * ldc + col] + v;
          Cf[row * ldc + col] = o;
          Cb[row * ldc + col] = (bf16_t)o;
        } else {  // EPI_RELU_RES
          float t = v + bias[col];
          t = t > 0.f ? t : 0.f;
          const float o = Res[row * ldc + col] + t;
          Cf[row * ldc + col] = o;
          Cb[row * ldc + col] = (bf16_t)o;
        }
      }
    }
  }
}

// ---------------------------------------------------------------------------
// Row softmax over S f32 values, in-place bf16 writeback (rows at f32 stride,
// so P is later read with lda = 2*S bf16 elems). One block (256 thr) per row.
// ---------------------------------------------------------------------------
__global__ __launch_bounds__(256) void softmax_rows(float* __restrict__ scores, int S)
{
  const long row = blockIdx.x;
  float* p = scores + row * (long)S;
  const int t = threadIdx.x;
  const int lane = t & 63, wave = t >> 6;

  float4 v0 = ((const float4*)p)[t * 2];
  float4 v1 = ((const float4*)p)[t * 2 + 1];
  float e[8] = {v0.x, v0.y, v0.z, v0.w, v1.x, v1.y, v1.z, v1.w};

  float m = e[0];
#pragma unroll
  for (int j = 1; j < 8; ++j) m = fmaxf(m, e[j]);
#pragma unroll
  for (int off = 32; off >= 1; off >>= 1) m = fmaxf(m, __shfl_xor(m, off));

  __shared__ float redm[4], reds[4];
  if (lane == 0) redm[wave] = m;
  __syncthreads();
  m = fmaxf(fmaxf(redm[0], redm[1]), fmaxf(redm[2], redm[3]));

  float s = 0.f;
#pragma unroll
  for (int j = 0; j < 8; ++j) { e[j] = __expf(e[j] - m); s += e[j]; }
#pragma unroll
  for (int off = 32; off >= 1; off >>= 1) s += __shfl_xor(s, off);
  if (lane == 0) reds[wave] = s;
  __syncthreads();
  s = reds[0] + reds[1] + reds[2] + reds[3];
  const float inv = 1.f / s;

  bf16x8_t ob;
#pragma unroll
  for (int j = 0; j < 8; ++j) ob[j] = (bf16_t)(e[j] * inv);
  ((bf16x8_t*)p)[t] = ob;
}

// ---------------------------------------------------------------------------
// f32 copy + bf16 cast (x -> xf, xb)
// ---------------------------------------------------------------------------
__global__ void cast_copy(const float* __restrict__ in, float* __restrict__ outf,
                          bf16_t* __restrict__ outb, long n4)
{
  long i = (long)blockIdx.x * blockDim.x + threadIdx.x;
  const long stride = (long)gridDim.x * blockDim.x;
  for (; i < n4; i += stride) {
    float4 v = ((const float4*)in)[i];
    ((float4*)outf)[i] = v;
    bf16x4_t bv;
    bv[0] = (bf16_t)v.x; bv[1] = (bf16_t)v.y; bv[2] = (bf16_t)v.z; bv[3] = (bf16_t)v.w;
    ((bf16x4_t*)outb)[i] = bv;
  }
}

// ---------------------------------------------------------------------------
// Batched f32 [R][C] -> bf16 [C][R] transpose-cast, 32x32 LDS tile
// ---------------------------------------------------------------------------
__global__ void transpose_cast(const float* __restrict__ in, long inBatch, int R, int C,
                               bf16_t* __restrict__ out, long outBatch)
{
  __shared__ float tile[32][33];
  const float* src = in + (long)blockIdx.z * inBatch;
  bf16_t* dst = out + (long)blockIdx.z * outBatch;
  const int c0 = blockIdx.x * 32, r0 = blockIdx.y * 32;
  const int tx = threadIdx.x, ty = threadIdx.y;
#pragma unroll
  for (int i = 0; i < 32; i += 8) tile[ty + i][tx] = src[(long)(r0 + ty + i) * C + (c0 + tx)];
  __syncthreads();
#pragma unroll
  for (int i = 0; i < 32; i += 8)
    dst[(long)(c0 + ty + i) * R + (r0 + tx)] = (bf16_t)tile[tx][ty + i];
}

// ---------------------------------------------------------------------------
extern "C" void kernel_launch(void* const* d_in, const int* in_sizes, int n_in,
                              void* d_out, int out_size, void* d_ws, size_t ws_size,
                              hipStream_t stream)
{
  constexpr int L = 4, NB = 4, S = 2048, D = 1024;
  const float* x  = (const float*)d_in[0];
  const float* W  = (const float*)d_in[1];
  const float* bv = (const float*)d_in[2];
  const float* Wo = (const float*)d_in[3];
  const float* bo = (const float*)d_in[4];

  // workspace layout (~186 MB)
  char* ws = (char*)d_ws;
  size_t off = 0;
  float* scores = (float*)(ws + off); off += (size_t)NB * S * S * 4;   // 67 MB
  float* xf = (float*)(ws + off); off += (size_t)NB * S * D * 4;       // 33.5 MB
  float* yf = (float*)(ws + off); off += (size_t)NB * S * D * 4;       // 33.5 MB
  bf16_t* xb  = (bf16_t*)(ws + off); off += (size_t)NB * S * D * 2;    // 16.7 MB
  bf16_t* xbT = (bf16_t*)(ws + off); off += (size_t)NB * S * D * 2;    // 16.7 MB
  bf16_t* yb  = (bf16_t*)(ws + off); off += (size_t)NB * S * D * 2;    // 16.7 MB
  bf16_t* WbT  = (bf16_t*)(ws + off); off += (size_t)L * D * D * 2;    // 8.4 MB
  bf16_t* WobT = (bf16_t*)(ws + off); off += (size_t)D * D * 2;        // 2 MB

  const long n4 = (long)NB * S * D / 4;
  cast_copy<<<2048, 256, 0, stream>>>(x, xf, xb, n4);
  transpose_cast<<<dim3(D / 32, S / 32, NB), dim3(32, 8), 0, stream>>>(
      x, (long)S * D, S, D, xbT, (long)D * S);
  transpose_cast<<<dim3(D / 32, D / 32, L), dim3(32, 8), 0, stream>>>(
      W, (long)D * D, D, D, WbT, (long)D * D);
  transpose_cast<<<dim3(D / 32, D / 32, 1), dim3(32, 8), 0, stream>>>(
      Wo, 0, D, D, WobT, 0);

  const float inv_sqrt_d = 0.03125f;  // 1/sqrt(1024)

  for (int i = 0; i < L; ++i) {
    // scores = xb @ xb^T * inv_sqrt_d  (Bt-layout is x itself)
    gemm_bt<EPI_SCALE><<<dim3(S / 128, S / 128, NB), 256, 0, stream>>>(
        xb, (long)S * D, D, xb, (long)S * D, D,
        scores, (long)S * S, S, nullptr, 0, nullptr, 0, nullptr,
        inv_sqrt_d, D);
    // softmax rows, in-place bf16 P (lda = 2*S)
    softmax_rows<<<NB * S, 256, 0, stream>>>(scores, S);
    // y = xf + P @ x   (Bt = xbT)
    gemm_bt<EPI_RES_BF16><<<dim3(D / 128, S / 128, NB), 256, 0, stream>>>(
        (const bf16_t*)scores, (long)2 * S * S, 2 * S, xbT, (long)D * S, S,
        yf, (long)S * D, D, yb, (long)S * D, xf, (long)S * D, nullptr,
        1.0f, S);
    // z = yf + relu(yb @ W[i] + b[i])  -> xf, xb   (batch-flattened M = NB*S)
    gemm_bt<EPI_RELU_RES><<<dim3(D / 128, (NB * S) / 128, 1), 256, 0, stream>>>(
        yb, 0, D, WbT + (size_t)i * D * D, 0, D,
        xf, 0, D, xb, 0, yf, 0, bv + (size_t)i * D,
        1.0f, D);
    if (i < L - 1)
      transpose_cast<<<dim3(D / 32, S / 32, NB), dim3(32, 8), 0, stream>>>(
          xf, (long)S * D, S, D, xbT, (long)D * S);
  }

  // out = xb @ Wo + bo
  gemm_bt<EPI_BIAS><<<dim3(D / 128, (NB * S) / 128, 1), 256, 0, stream>>>(
      xb, 0, D, WobT, 0, D,
      (float*)d_out, 0, D, nullptr, 0, nullptr, 0, bo,
      1.0f, D);
}

// Round 3
// 705.357 us; speedup vs baseline: 1.2366x; 1.1721x over previous
//
#include <hip/hip_runtime.h>
#include <hip/hip_bf16.h>

typedef __bf16 bf16_t;
typedef __bf16 bf16x8_t __attribute__((ext_vector_type(8)));
typedef __bf16 bf16x4_t __attribute__((ext_vector_type(4)));
typedef float f32x4_t __attribute__((ext_vector_type(4)));

#define EPI_SCALE 0
#define EPI_RES_BF16 1
#define EPI_RELU_RES 2
#define EPI_BIAS 3

// async 16B global -> LDS (gfx950 global_load_lds_dwordx4)
__device__ __forceinline__ void gload_lds16(const bf16_t* g, bf16_t* l) {
  __builtin_amdgcn_global_load_lds(
      (const __attribute__((address_space(1))) void*)g,
      (__attribute__((address_space(3))) void*)l, 16, 0, 0);
}

// ---------------------------------------------------------------------------
// Tiled bf16 MFMA GEMM, B given TRANSPOSED (Bt is [N][K]).
// C[M,N] = epilogue(A[M,K] @ Bt^T * alpha).
// Block = 256 threads = 4 waves (2x2), tile 128x128, BK=32.
// 2-phase double-buffered prefetch: STAGE(t+1) issued BEFORE compute(t);
// the single __syncthreads per iter (implicit vmcnt(0)+lgkmcnt(0) drain)
// provides ordering. XCD-aware block swizzle for L2 panel reuse.
// ---------------------------------------------------------------------------
template <int EPI>
__global__ __launch_bounds__(256) void gemm_bt(
    const bf16_t* __restrict__ A, long aBatch, int lda,
    const bf16_t* __restrict__ Bt, long bBatch, int ldb,
    float* __restrict__ Cf, long cfBatch, int ldc,
    bf16_t* __restrict__ Cb, long cbBatch,
    const float* __restrict__ Res, long resBatch,
    const float* __restrict__ bias,
    float alpha, int K)
{
  // ---- XCD-aware bijective swizzle (nwg % 8 == 0 for all our launches) ----
  const unsigned gx = gridDim.x, gy = gridDim.y;
  const unsigned nwg = gx * gy * gridDim.z;
  const unsigned lin = blockIdx.x + gx * (blockIdx.y + gy * blockIdx.z);
  const unsigned swz = (lin & 7u) * (nwg >> 3) + (lin >> 3);
  const unsigned bx = swz % gx;
  const unsigned tq = swz / gx;
  const unsigned by = tq % gy;
  const unsigned bz = tq / gy;

  A += (long)bz * aBatch;
  Bt += (long)bz * bBatch;
  Cf += (long)bz * cfBatch;
  if (Cb) Cb += (long)bz * cbBatch;
  if (Res) Res += (long)bz * resBatch;

  __shared__ bf16_t shA[2][128 * 32];  // linear: global_load_lds writes base+lane*16B
  __shared__ bf16_t shB[2][128 * 32];

  const int tid = threadIdx.x;
  const int wave = tid >> 6, lane = tid & 63;
  const int wm = wave >> 1, wn = wave & 1;
  const int lr = lane & 15, lh = lane >> 4;

  // staging geometry: wave w, issue j covers rows w*16 + j*64 .. +15
  const int srow = wave * 16 + (lane >> 2);  // + j*64
  const int scol = (lane & 3) << 3;          // 0,8,16,24 elems
  const bf16_t* Ag = A + (long)(by * 128 + srow) * lda + scol;
  const bf16_t* Bg = Bt + (long)(bx * 128 + srow) * ldb + scol;
  const int ldsOff = wave * 16 * 32;  // wave-uniform dest, +j*64*32

  f32x4_t acc[4][4] = {};

  const int nk = K >> 5;

  // prologue: stage tile 0
  {
    bf16_t* la = shA[0] + ldsOff;
    bf16_t* lb = shB[0] + ldsOff;
    gload_lds16(Ag, la);
    gload_lds16(Ag + 64 * lda, la + 64 * 32);
    gload_lds16(Bg, lb);
    gload_lds16(Bg + 64 * ldb, lb + 64 * 32);
  }
  __syncthreads();

  int cur = 0;
  for (int kt = 0; kt < nk; ++kt) {
    // prefetch next K-tile into the other buffer (overlaps with compute below)
    if (kt + 1 < nk) {
      const long k1 = (long)(kt + 1) << 5;
      bf16_t* la = shA[cur ^ 1] + ldsOff;
      bf16_t* lb = shB[cur ^ 1] + ldsOff;
      gload_lds16(Ag + k1, la);
      gload_lds16(Ag + 64 * lda + k1, la + 64 * 32);
      gload_lds16(Bg + k1, lb);
      gload_lds16(Bg + 64 * ldb + k1, lb + 64 * 32);
    }

    bf16x8_t af[4], bfr[4];
#pragma unroll
    for (int m = 0; m < 4; ++m)
      af[m] = *(const bf16x8_t*)(shA[cur] + (wm * 64 + m * 16 + lr) * 32 + lh * 8);
#pragma unroll
    for (int n = 0; n < 4; ++n)
      bfr[n] = *(const bf16x8_t*)(shB[cur] + (wn * 64 + n * 16 + lr) * 32 + lh * 8);
#pragma unroll
    for (int m = 0; m < 4; ++m)
#pragma unroll
      for (int n = 0; n < 4; ++n)
        acc[m][n] = __builtin_amdgcn_mfma_f32_16x16x32_bf16(af[m], bfr[n], acc[m][n], 0, 0, 0);

    __syncthreads();  // drains vmcnt+lgkmcnt: prefetched tile ready, reads done
    cur ^= 1;
  }

  // ---- epilogue: C/D layout col = lane&15, row = (lane>>4)*4 + reg ----
  const long gr0 = (long)by * 128 + wm * 64;
  const int gc0 = bx * 128 + wn * 64;
#pragma unroll
  for (int m = 0; m < 4; ++m) {
#pragma unroll
    for (int n = 0; n < 4; ++n) {
#pragma unroll
      for (int r = 0; r < 4; ++r) {
        const long row = gr0 + m * 16 + lh * 4 + r;
        const int col = gc0 + n * 16 + lr;
        const float v = acc[m][n][r];
        if constexpr (EPI == EPI_SCALE) {
          Cf[row * ldc + col] = v * alpha;
        } else if constexpr (EPI == EPI_BIAS) {
          Cf[row * ldc + col] = v + bias[col];
        } else if constexpr (EPI == EPI_RES_BF16) {
          const float o = Res[row * ldc + col] + v;
          Cf[row * ldc + col] = o;
          Cb[row * ldc + col] = (bf16_t)o;
        } else {  // EPI_RELU_RES
          float t = v + bias[col];
          t = t > 0.f ? t : 0.f;
          const float o = Res[row * ldc + col] + t;
          Cf[row * ldc + col] = o;
          Cb[row * ldc + col] = (bf16_t)o;
        }
      }
    }
  }
}

// ---------------------------------------------------------------------------
// Row softmax over S f32 values, in-place bf16 writeback (rows at f32 stride,
// so P is later read with lda = 2*S bf16 elems). One block (256 thr) per row.
// ---------------------------------------------------------------------------
__global__ __launch_bounds__(256) void softmax_rows(float* __restrict__ scores, int S)
{
  const long row = blockIdx.x;
  float* p = scores + row * (long)S;
  const int t = threadIdx.x;
  const int lane = t & 63, wave = t >> 6;

  float4 v0 = ((const float4*)p)[t * 2];
  float4 v1 = ((const float4*)p)[t * 2 + 1];
  float e[8] = {v0.x, v0.y, v0.z, v0.w, v1.x, v1.y, v1.z, v1.w};

  float m = e[0];
#pragma unroll
  for (int j = 1; j < 8; ++j) m = fmaxf(m, e[j]);
#pragma unroll
  for (int off = 32; off >= 1; off >>= 1) m = fmaxf(m, __shfl_xor(m, off));

  __shared__ float redm[4], reds[4];
  if (lane == 0) redm[wave] = m;
  __syncthreads();
  m = fmaxf(fmaxf(redm[0], redm[1]), fmaxf(redm[2], redm[3]));

  float s = 0.f;
#pragma unroll
  for (int j = 0; j < 8; ++j) { e[j] = __expf(e[j] - m); s += e[j]; }
#pragma unroll
  for (int off = 32; off >= 1; off >>= 1) s += __shfl_xor(s, off);
  if (lane == 0) reds[wave] = s;
  __syncthreads();
  s = reds[0] + reds[1] + reds[2] + reds[3];
  const float inv = 1.f / s;

  bf16x8_t ob;
#pragma unroll
  for (int j = 0; j < 8; ++j) ob[j] = (bf16_t)(e[j] * inv);
  ((bf16x8_t*)p)[t] = ob;
}

// ---------------------------------------------------------------------------
// f32 copy + bf16 cast (x -> xf, xb)
// ---------------------------------------------------------------------------
__global__ void cast_copy(const float* __restrict__ in, float* __restrict__ outf,
                          bf16_t* __restrict__ outb, long n4)
{
  long i = (long)blockIdx.x * blockDim.x + threadIdx.x;
  const long stride = (long)gridDim.x * blockDim.x;
  for (; i < n4; i += stride) {
    float4 v = ((const float4*)in)[i];
    ((float4*)outf)[i] = v;
    bf16x4_t bv;
    bv[0] = (bf16_t)v.x; bv[1] = (bf16_t)v.y; bv[2] = (bf16_t)v.z; bv[3] = (bf16_t)v.w;
    ((bf16x4_t*)outb)[i] = bv;
  }
}

// ---------------------------------------------------------------------------
// Batched f32 [R][C] -> bf16 [C][R] transpose-cast, 32x32 LDS tile
// ---------------------------------------------------------------------------
__global__ void transpose_cast(const float* __restrict__ in, long inBatch, int R, int C,
                               bf16_t* __restrict__ out, long outBatch)
{
  __shared__ float tile[32][33];
  const float* src = in + (long)blockIdx.z * inBatch;
  bf16_t* dst = out + (long)blockIdx.z * outBatch;
  const int c0 = blockIdx.x * 32, r0 = blockIdx.y * 32;
  const int tx = threadIdx.x, ty = threadIdx.y;
#pragma unroll
  for (int i = 0; i < 32; i += 8) tile[ty + i][tx] = src[(long)(r0 + ty + i) * C + (c0 + tx)];
  __syncthreads();
#pragma unroll
  for (int i = 0; i < 32; i += 8)
    dst[(long)(c0 + ty + i) * R + (r0 + tx)] = (bf16_t)tile[tx][ty + i];
}

// ---------------------------------------------------------------------------
extern "C" void kernel_launch(void* const* d_in, const int* in_sizes, int n_in,
                              void* d_out, int out_size, void* d_ws, size_t ws_size,
                              hipStream_t stream)
{
  constexpr int L = 4, NB = 4, S = 2048, D = 1024;
  const float* x  = (const float*)d_in[0];
  const float* W  = (const float*)d_in[1];
  const float* bv = (const float*)d_in[2];
  const float* Wo = (const float*)d_in[3];
  const float* bo = (const float*)d_in[4];

  // workspace layout (~186 MB)
  char* ws = (char*)d_ws;
  size_t off = 0;
  float* scores = (float*)(ws + off); off += (size_t)NB * S * S * 4;   // 67 MB
  float* xf = (float*)(ws + off); off += (size_t)NB * S * D * 4;       // 33.5 MB
  float* yf = (float*)(ws + off); off += (size_t)NB * S * D * 4;       // 33.5 MB
  bf16_t* xb  = (bf16_t*)(ws + off); off += (size_t)NB * S * D * 2;    // 16.7 MB
  bf16_t* xbT = (bf16_t*)(ws + off); off += (size_t)NB * S * D * 2;    // 16.7 MB
  bf16_t* yb  = (bf16_t*)(ws + off); off += (size_t)NB * S * D * 2;    // 16.7 MB
  bf16_t* WbT  = (bf16_t*)(ws + off); off += (size_t)L * D * D * 2;    // 8.4 MB
  bf16_t* WobT = (bf16_t*)(ws + off); off += (size_t)D * D * 2;        // 2 MB

  const long n4 = (long)NB * S * D / 4;
  cast_copy<<<2048, 256, 0, stream>>>(x, xf, xb, n4);
  transpose_cast<<<dim3(D / 32, S / 32, NB), dim3(32, 8), 0, stream>>>(
      x, (long)S * D, S, D, xbT, (long)D * S);
  transpose_cast<<<dim3(D / 32, D / 32, L), dim3(32, 8), 0, stream>>>(
      W, (long)D * D, D, D, WbT, (long)D * D);
  transpose_cast<<<dim3(D / 32, D / 32, 1), dim3(32, 8), 0, stream>>>(
      Wo, 0, D, D, WobT, 0);

  const float inv_sqrt_d = 0.03125f;  // 1/sqrt(1024)

  for (int i = 0; i < L; ++i) {
    // scores = xb @ xb^T * inv_sqrt_d  (Bt-layout is x itself)
    gemm_bt<EPI_SCALE><<<dim3(S / 128, S / 128, NB), 256, 0, stream>>>(
        xb, (long)S * D, D, xb, (long)S * D, D,
        scores, (long)S * S, S, nullptr, 0, nullptr, 0, nullptr,
        inv_sqrt_d, D);
    // softmax rows, in-place bf16 P (lda = 2*S)
    softmax_rows<<<NB * S, 256, 0, stream>>>(scores, S);
    // y = xf + P @ x   (Bt = xbT)
    gemm_bt<EPI_RES_BF16><<<dim3(D / 128, S / 128, NB), 256, 0, stream>>>(
        (const bf16_t*)scores, (long)2 * S * S, 2 * S, xbT, (long)D * S, S,
        yf, (long)S * D, D, yb, (long)S * D, xf, (long)S * D, nullptr,
        1.0f, S);
    // z = yf + relu(yb @ W[i] + b[i])  -> xf, xb   (batch-flattened M = NB*S)
    gemm_bt<EPI_RELU_RES><<<dim3(D / 128, (NB * S) / 128, 1), 256, 0, stream>>>(
        yb, 0, D, WbT + (size_t)i * D * D, 0, D,
        xf, 0, D, xb, 0, yf, 0, bv + (size_t)i * D,
        1.0f, D);
    if (i < L - 1)
      transpose_cast<<<dim3(D / 32, S / 32, NB), dim3(32, 8), 0, stream>>>(
          xf, (long)S * D, S, D, xbT, (long)D * S);
  }

  // out = xb @ Wo + bo
  gemm_bt<EPI_BIAS><<<dim3(D / 128, (NB * S) / 128, 1), 256, 0, stream>>>(
      xb, 0, D, WobT, 0, D,
      (float*)d_out, 0, D, nullptr, 0, nullptr, 0, bo,
      1.0f, D);
}

// Round 4
// 654.796 us; speedup vs baseline: 1.3321x; 1.0772x over previous
//
#include <hip/hip_runtime.h>
#include <hip/hip_bf16.h>

typedef __bf16 bf16_t;
typedef __bf16 bf16x8_t __attribute__((ext_vector_type(8)));
typedef __bf16 bf16x4_t __attribute__((ext_vector_type(4)));
typedef float f32x4_t __attribute__((ext_vector_type(4)));

#define EPI_SCALE 0
#define EPI_RES_BF16 1
#define EPI_RELU_RES 2
#define EPI_BIAS 3

// async 16B global -> LDS (gfx950 global_load_lds_dwordx4)
__device__ __forceinline__ void gload_lds16(const bf16_t* g, bf16_t* l) {
  __builtin_amdgcn_global_load_lds(
      (const __attribute__((address_space(1))) void*)g,
      (__attribute__((address_space(3))) void*)l, 16, 0, 0);
}

__device__ __forceinline__ bf16x8_t ds_read_b128_bf16(unsigned addr) {
  bf16x8_t r;
  asm volatile("ds_read_b128 %0, %1" : "=v"(r) : "v"(addr));
  return r;
}

#define WAIT_VM(n) asm volatile("s_waitcnt vmcnt(" #n ")" ::: "memory")
#define WAIT_LGKM0 asm volatile("s_waitcnt lgkmcnt(0)" ::: "memory")
#define SCHED_FENCE __builtin_amdgcn_sched_barrier(0)

// ===========================================================================
// 256x256 8-phase bf16 GEMM (scores): C = alpha * A @ Bt^T, K multiple of 64,
// grid (N/256, M/256, batch), 512 threads = 8 waves (2M x 4N), BK=64.
// LDS 128 KiB dynamic: A/B double-buffered as 4 ring chunks (256x32 each).
// Counted vmcnt(8) (never 0 in steady state), raw s_barrier, T2 XOR-swizzle
// (pre-swizzled global source + XOR'd ds_read addr), T5 setprio.
// Requires nt = K/64 >= 3.
// ===========================================================================
__global__ __launch_bounds__(512) void gemm256_bt_scale(
    const bf16_t* __restrict__ A, long aBatch, int lda,
    const bf16_t* __restrict__ Bt, long bBatch, int ldb,
    float* __restrict__ C, long cBatch, int ldc,
    float alpha, int K)
{
  extern __shared__ char smem[];
  typedef __attribute__((address_space(3))) char lds_char_t;
  const unsigned ldsBase = (unsigned)(size_t)(lds_char_t*)smem;

  // ---- XCD-aware bijective swizzle (nwg % 8 == 0) ----
  const unsigned gx = gridDim.x, gy = gridDim.y;
  const unsigned nwg = gx * gy * gridDim.z;
  const unsigned lin = blockIdx.x + gx * (blockIdx.y + gy * blockIdx.z);
  const unsigned swz = (lin & 7u) * (nwg >> 3) + (lin >> 3);
  const unsigned bx = swz % gx;
  const unsigned tq = swz / gx;
  const unsigned by = tq % gy;
  const unsigned bz = tq / gy;

  A += (long)bz * aBatch;
  Bt += (long)bz * bBatch;
  C += (long)bz * cBatch;

  const int tid = threadIdx.x, wid = tid >> 6, lane = tid & 63;
  const int wm = wid >> 2, wn = wid & 3;     // 2M x 4N waves; per-wave out 128x64
  const int lr = lane & 15, lh = lane >> 4;
  const int sw2 = ((lr >> 3) & 1) << 1;      // read-side swizzle (row bit3)
  const unsigned cbyte = (unsigned)((lh ^ sw2) << 4);

  // staging geometry: thread covers row grow + j*128, 8 cols at gcol (pre-swizzled)
  const int gsw = ((lane >> 5) & 1) << 1;    // row bit3 of staged row
  const int gcol = ((lane & 3) ^ gsw) << 3;
  const int grow = wid * 16 + (lane >> 2);
  const bf16_t* Ag = A + (long)(by * 256 + grow) * lda + gcol;
  const bf16_t* Bg = Bt + (long)(bx * 256 + grow) * ldb + gcol;

  // LDS arena: A chunks at b*32768 + h*16384; B at +65536. Chunk = 256x32 bf16.
#define STAGE_A(KT, H, B_) do { \
    const bf16_t* _s = Ag + (long)(KT) * 64 + (H) * 32; \
    bf16_t* _d = (bf16_t*)(smem + (B_) * 32768 + (H) * 16384 + wid * 1024); \
    gload_lds16(_s, _d); \
    gload_lds16(_s + (long)128 * lda, (bf16_t*)((char*)_d + 8192)); \
  } while (0)
#define STAGE_B(KT, H, B_) do { \
    const bf16_t* _s = Bg + (long)(KT) * 64 + (H) * 32; \
    bf16_t* _d = (bf16_t*)(smem + 65536 + (B_) * 32768 + (H) * 16384 + wid * 1024); \
    gload_lds16(_s, _d); \
    gload_lds16(_s + (long)128 * ldb, (bf16_t*)((char*)_d + 8192)); \
  } while (0)

  const unsigned aAddr = ldsBase + (unsigned)((wm * 128 + lr) * 64) + cbyte;
  const unsigned bAddr = ldsBase + 65536u + (unsigned)((wn * 64 + lr) * 64) + cbyte;

  bf16x8_t aF[4], bF[4];
  f32x4_t acc[8][4] = {};

#define MFMA16(MH) do { \
    __builtin_amdgcn_s_setprio(1); \
    _Pragma("unroll") for (int _n = 0; _n < 4; ++_n) \
      _Pragma("unroll") for (int _m = 0; _m < 4; ++_m) \
        acc[(MH) * 4 + _m][_n] = __builtin_amdgcn_mfma_f32_16x16x32_bf16( \
            aF[_m], bF[_n], acc[(MH) * 4 + _m][_n], 0, 0, 0); \
    __builtin_amdgcn_s_setprio(0); \
  } while (0)

  // phase: ds_read frags -> stage issue -> [vm wait] -> barrier -> lgkm0 -> MFMA -> barrier
#define PHASE(MH, H, B_, STAGE_STMT, VM_STMT) do { \
    _Pragma("unroll") for (int _m = 0; _m < 4; ++_m) \
      aF[_m] = ds_read_b128_bf16(aAddr + (unsigned)(B_)*32768u + (H)*16384u + ((MH)*4 + _m)*1024u); \
    if ((MH) == 0) { \
      _Pragma("unroll") for (int _n = 0; _n < 4; ++_n) \
        bF[_n] = ds_read_b128_bf16(bAddr + (unsigned)(B_)*32768u + (H)*16384u + _n*1024u); \
    } \
    STAGE_STMT; \
    VM_STMT; \
    __builtin_amdgcn_s_barrier(); \
    WAIT_LGKM0; \
    SCHED_FENCE; \
    MFMA16(MH); \
    __builtin_amdgcn_s_barrier(); \
    SCHED_FENCE; \
  } while (0)

  const int nt = K >> 6;  // >= 3

  // prologue: K-tile 0 fully + K-tile 1 h0 chunks; then wait oldest 4 loads
  STAGE_A(0, 0, 0); STAGE_B(0, 0, 0); STAGE_A(0, 1, 0); STAGE_B(0, 1, 0);
  STAGE_A(1, 0, 1); STAGE_B(1, 0, 1);
  WAIT_VM(8);
  __builtin_amdgcn_s_barrier();
  SCHED_FENCE;

  int bufc = 0;
  for (int kt = 0; kt < nt; ++kt, bufc ^= 1) {
    const int bo = bufc ^ 1;
    const bool st12 = (kt + 1 < nt);
    const bool st34 = (kt + 2 < nt);
    PHASE(0, 0, bufc, if (st12) STAGE_A(kt + 1, 1, bo), );
    PHASE(1, 0, bufc, if (st12) STAGE_B(kt + 1, 1, bo),
          if (kt == nt - 1) { WAIT_VM(0); } else { WAIT_VM(8); });
    PHASE(0, 1, bufc, if (st34) STAGE_A(kt + 2, 0, bufc), );
    PHASE(1, 1, bufc, if (st34) STAGE_B(kt + 2, 0, bufc),
          if (kt < nt - 2) { WAIT_VM(8); } else { WAIT_VM(4); });
  }

  // epilogue: C/D layout col = lane&15, row = (lane>>4)*4 + reg
  const long r0 = (long)by * 256 + wm * 128;
  const int c0 = bx * 256 + wn * 64;
#pragma unroll
  for (int m = 0; m < 8; ++m)
#pragma unroll
    for (int n = 0; n < 4; ++n)
#pragma unroll
      for (int r = 0; r < 4; ++r)
        C[(r0 + m * 16 + lh * 4 + r) * ldc + c0 + n * 16 + lr] = acc[m][n][r] * alpha;

#undef PHASE
#undef MFMA16
#undef STAGE_A
#undef STAGE_B
}

// ---------------------------------------------------------------------------
// Tiled bf16 MFMA GEMM (2-phase dbuf), B given TRANSPOSED (Bt is [N][K]).
// Used for PV / FFN / final projection (grids too small for 256^2).
// ---------------------------------------------------------------------------
template <int EPI>
__global__ __launch_bounds__(256) void gemm_bt(
    const bf16_t* __restrict__ A, long aBatch, int lda,
    const bf16_t* __restrict__ Bt, long bBatch, int ldb,
    float* __restrict__ Cf, long cfBatch, int ldc,
    bf16_t* __restrict__ Cb, long cbBatch,
    const float* __restrict__ Res, long resBatch,
    const float* __restrict__ bias,
    float alpha, int K)
{
  const unsigned gx = gridDim.x, gy = gridDim.y;
  const unsigned nwg = gx * gy * gridDim.z;
  const unsigned lin = blockIdx.x + gx * (blockIdx.y + gy * blockIdx.z);
  const unsigned swz = (lin & 7u) * (nwg >> 3) + (lin >> 3);
  const unsigned bx = swz % gx;
  const unsigned tq = swz / gx;
  const unsigned by = tq % gy;
  const unsigned bz = tq / gy;

  A += (long)bz * aBatch;
  Bt += (long)bz * bBatch;
  Cf += (long)bz * cfBatch;
  if (Cb) Cb += (long)bz * cbBatch;
  if (Res) Res += (long)bz * resBatch;

  __shared__ bf16_t shA[2][128 * 32];
  __shared__ bf16_t shB[2][128 * 32];

  const int tid = threadIdx.x;
  const int wave = tid >> 6, lane = tid & 63;
  const int wm = wave >> 1, wn = wave & 1;
  const int lr = lane & 15, lh = lane >> 4;

  const int srow = wave * 16 + (lane >> 2);
  const int scol = (lane & 3) << 3;
  const bf16_t* Ag = A + (long)(by * 128 + srow) * lda + scol;
  const bf16_t* Bg = Bt + (long)(bx * 128 + srow) * ldb + scol;
  const int ldsOff = wave * 16 * 32;

  f32x4_t acc[4][4] = {};

  const int nk = K >> 5;
  {
    bf16_t* la = shA[0] + ldsOff;
    bf16_t* lb = shB[0] + ldsOff;
    gload_lds16(Ag, la);
    gload_lds16(Ag + 64 * lda, la + 64 * 32);
    gload_lds16(Bg, lb);
    gload_lds16(Bg + 64 * ldb, lb + 64 * 32);
  }
  __syncthreads();

  int cur = 0;
  for (int kt = 0; kt < nk; ++kt) {
    if (kt + 1 < nk) {
      const long k1 = (long)(kt + 1) << 5;
      bf16_t* la = shA[cur ^ 1] + ldsOff;
      bf16_t* lb = shB[cur ^ 1] + ldsOff;
      gload_lds16(Ag + k1, la);
      gload_lds16(Ag + 64 * lda + k1, la + 64 * 32);
      gload_lds16(Bg + k1, lb);
      gload_lds16(Bg + 64 * ldb + k1, lb + 64 * 32);
    }

    bf16x8_t af[4], bfr[4];
#pragma unroll
    for (int m = 0; m < 4; ++m)
      af[m] = *(const bf16x8_t*)(shA[cur] + (wm * 64 + m * 16 + lr) * 32 + lh * 8);
#pragma unroll
    for (int n = 0; n < 4; ++n)
      bfr[n] = *(const bf16x8_t*)(shB[cur] + (wn * 64 + n * 16 + lr) * 32 + lh * 8);
#pragma unroll
    for (int m = 0; m < 4; ++m)
#pragma unroll
      for (int n = 0; n < 4; ++n)
        acc[m][n] = __builtin_amdgcn_mfma_f32_16x16x32_bf16(af[m], bfr[n], acc[m][n], 0, 0, 0);

    __syncthreads();
    cur ^= 1;
  }

  const long gr0 = (long)by * 128 + wm * 64;
  const int gc0 = bx * 128 + wn * 64;
#pragma unroll
  for (int m = 0; m < 4; ++m) {
#pragma unroll
    for (int n = 0; n < 4; ++n) {
#pragma unroll
      for (int r = 0; r < 4; ++r) {
        const long row = gr0 + m * 16 + lh * 4 + r;
        const int col = gc0 + n * 16 + lr;
        const float v = acc[m][n][r];
        if constexpr (EPI == EPI_SCALE) {
          Cf[row * ldc + col] = v * alpha;
        } else if constexpr (EPI == EPI_BIAS) {
          Cf[row * ldc + col] = v + bias[col];
        } else if constexpr (EPI == EPI_RES_BF16) {
          const float o = Res[row * ldc + col] + v;
          Cf[row * ldc + col] = o;
          Cb[row * ldc + col] = (bf16_t)o;
        } else {
          float t = v + bias[col];
          t = t > 0.f ? t : 0.f;
          const float o = Res[row * ldc + col] + t;
          Cf[row * ldc + col] = o;
          Cb[row * ldc + col] = (bf16_t)o;
        }
      }
    }
  }
}

// ---------------------------------------------------------------------------
// Row softmax over S f32 values, in-place bf16 writeback (rows at f32 stride,
// so P is later read with lda = 2*S bf16 elems). One block (256 thr) per row.
// ---------------------------------------------------------------------------
__global__ __launch_bounds__(256) void softmax_rows(float* __restrict__ scores, int S)
{
  const long row = blockIdx.x;
  float* p = scores + row * (long)S;
  const int t = threadIdx.x;
  const int lane = t & 63, wave = t >> 6;

  float4 v0 = ((const float4*)p)[t * 2];
  float4 v1 = ((const float4*)p)[t * 2 + 1];
  float e[8] = {v0.x, v0.y, v0.z, v0.w, v1.x, v1.y, v1.z, v1.w};

  float m = e[0];
#pragma unroll
  for (int j = 1; j < 8; ++j) m = fmaxf(m, e[j]);
#pragma unroll
  for (int off = 32; off >= 1; off >>= 1) m = fmaxf(m, __shfl_xor(m, off));

  __shared__ float redm[4], reds[4];
  if (lane == 0) redm[wave] = m;
  __syncthreads();
  m = fmaxf(fmaxf(redm[0], redm[1]), fmaxf(redm[2], redm[3]));

  float s = 0.f;
#pragma unroll
  for (int j = 0; j < 8; ++j) { e[j] = __expf(e[j] - m); s += e[j]; }
#pragma unroll
  for (int off = 32; off >= 1; off >>= 1) s += __shfl_xor(s, off);
  if (lane == 0) reds[wave] = s;
  __syncthreads();
  s = reds[0] + reds[1] + reds[2] + reds[3];
  const float inv = 1.f / s;

  bf16x8_t ob;
#pragma unroll
  for (int j = 0; j < 8; ++j) ob[j] = (bf16_t)(e[j] * inv);
  ((bf16x8_t*)p)[t] = ob;
}

// ---------------------------------------------------------------------------
__global__ void cast_copy(const float* __restrict__ in, float* __restrict__ outf,
                          bf16_t* __restrict__ outb, long n4)
{
  long i = (long)blockIdx.x * blockDim.x + threadIdx.x;
  const long stride = (long)gridDim.x * blockDim.x;
  for (; i < n4; i += stride) {
    float4 v = ((const float4*)in)[i];
    ((float4*)outf)[i] = v;
    bf16x4_t bv;
    bv[0] = (bf16_t)v.x; bv[1] = (bf16_t)v.y; bv[2] = (bf16_t)v.z; bv[3] = (bf16_t)v.w;
    ((bf16x4_t*)outb)[i] = bv;
  }
}

// ---------------------------------------------------------------------------
__global__ void transpose_cast(const float* __restrict__ in, long inBatch, int R, int C,
                               bf16_t* __restrict__ out, long outBatch)
{
  __shared__ float tile[32][33];
  const float* src = in + (long)blockIdx.z * inBatch;
  bf16_t* dst = out + (long)blockIdx.z * outBatch;
  const int c0 = blockIdx.x * 32, r0 = blockIdx.y * 32;
  const int tx = threadIdx.x, ty = threadIdx.y;
#pragma unroll
  for (int i = 0; i < 32; i += 8) tile[ty + i][tx] = src[(long)(r0 + ty + i) * C + (c0 + tx)];
  __syncthreads();
#pragma unroll
  for (int i = 0; i < 32; i += 8)
    dst[(long)(c0 + ty + i) * R + (r0 + tx)] = (bf16_t)tile[tx][ty + i];
}

// ---------------------------------------------------------------------------
extern "C" void kernel_launch(void* const* d_in, const int* in_sizes, int n_in,
                              void* d_out, int out_size, void* d_ws, size_t ws_size,
                              hipStream_t stream)
{
  constexpr int L = 4, NB = 4, S = 2048, D = 1024;
  const float* x  = (const float*)d_in[0];
  const float* W  = (const float*)d_in[1];
  const float* bv = (const float*)d_in[2];
  const float* Wo = (const float*)d_in[3];
  const float* bo = (const float*)d_in[4];

  char* ws = (char*)d_ws;
  size_t off = 0;
  float* scores = (float*)(ws + off); off += (size_t)NB * S * S * 4;
  float* xf = (float*)(ws + off); off += (size_t)NB * S * D * 4;
  float* yf = (float*)(ws + off); off += (size_t)NB * S * D * 4;
  bf16_t* xb  = (bf16_t*)(ws + off); off += (size_t)NB * S * D * 2;
  bf16_t* xbT = (bf16_t*)(ws + off); off += (size_t)NB * S * D * 2;
  bf16_t* yb  = (bf16_t*)(ws + off); off += (size_t)NB * S * D * 2;
  bf16_t* WbT  = (bf16_t*)(ws + off); off += (size_t)L * D * D * 2;
  bf16_t* WobT = (bf16_t*)(ws + off); off += (size_t)D * D * 2;

  hipFuncSetAttribute((const void*)gemm256_bt_scale,
                      hipFuncAttributeMaxDynamicSharedMemorySize, 131072);

  const long n4 = (long)NB * S * D / 4;
  cast_copy<<<2048, 256, 0, stream>>>(x, xf, xb, n4);
  transpose_cast<<<dim3(D / 32, S / 32, NB), dim3(32, 8), 0, stream>>>(
      x, (long)S * D, S, D, xbT, (long)D * S);
  transpose_cast<<<dim3(D / 32, D / 32, L), dim3(32, 8), 0, stream>>>(
      W, (long)D * D, D, D, WbT, (long)D * D);
  transpose_cast<<<dim3(D / 32, D / 32, 1), dim3(32, 8), 0, stream>>>(
      Wo, 0, D, D, WobT, 0);

  const float inv_sqrt_d = 0.03125f;  // 1/sqrt(1024)

  for (int i = 0; i < L; ++i) {
    // scores = xb @ xb^T * inv_sqrt_d  (256^2 8-phase kernel)
    gemm256_bt_scale<<<dim3(S / 256, S / 256, NB), 512, 131072, stream>>>(
        xb, (long)S * D, D, xb, (long)S * D, D,
        scores, (long)S * S, S, inv_sqrt_d, D);
    // softmax rows, in-place bf16 P (lda = 2*S)
    softmax_rows<<<NB * S, 256, 0, stream>>>(scores, S);
    // y = xf + P @ x   (Bt = xbT)
    gemm_bt<EPI_RES_BF16><<<dim3(D / 128, S / 128, NB), 256, 0, stream>>>(
        (const bf16_t*)scores, (long)2 * S * S, 2 * S, xbT, (long)D * S, S,
        yf, (long)S * D, D, yb, (long)S * D, xf, (long)S * D, nullptr,
        1.0f, S);
    // z = yf + relu(yb @ W[i] + b[i])  -> xf, xb
    gemm_bt<EPI_RELU_RES><<<dim3(D / 128, (NB * S) / 128, 1), 256, 0, stream>>>(
        yb, 0, D, WbT + (size_t)i * D * D, 0, D,
        xf, 0, D, xb, 0, yf, 0, bv + (size_t)i * D,
        1.0f, D);
    if (i < L - 1)
      transpose_cast<<<dim3(D / 32, S / 32, NB), dim3(32, 8), 0, stream>>>(
          xf, (long)S * D, S, D, xbT, (long)D * S);
  }

  // out = xb @ Wo + bo
  gemm_bt<EPI_BIAS><<<dim3(D / 128, (NB * S) / 128, 1), 256, 0, stream>>>(
      xb, 0, D, WobT, 0, D,
      (float*)d_out, 0, D, nullptr, 0, nullptr, 0, bo,
      1.0f, D);
}

// Round 5
// 605.695 us; speedup vs baseline: 1.4401x; 1.0811x over previous
//
#include <hip/hip_runtime.h>
#include <hip/hip_bf16.h>

typedef __bf16 bf16_t;
typedef __bf16 bf16x8_t __attribute__((ext_vector_type(8)));
typedef __bf16 bf16x4_t __attribute__((ext_vector_type(4)));
typedef float f32x4_t __attribute__((ext_vector_type(4)));

#define EPI_SCALE 0
#define EPI_RES_BF16 1
#define EPI_RELU_RES 2
#define EPI_BIAS 3

// async 16B global -> LDS (gfx950 global_load_lds_dwordx4)
__device__ __forceinline__ void gload_lds16(const bf16_t* g, bf16_t* l) {
  __builtin_amdgcn_global_load_lds(
      (const __attribute__((address_space(1))) void*)g,
      (__attribute__((address_space(3))) void*)l, 16, 0, 0);
}

__device__ __forceinline__ bf16x8_t ds_read_b128_bf16(unsigned addr) {
  bf16x8_t r;
  asm volatile("ds_read_b128 %0, %1" : "=v"(r) : "v"(addr));
  return r;
}

#define WAIT_VM(n) asm volatile("s_waitcnt vmcnt(" #n ")" ::: "memory")
#define WAIT_LGKM0 asm volatile("s_waitcnt lgkmcnt(0)" ::: "memory")
#define SCHED_FENCE __builtin_amdgcn_sched_barrier(0)

// ===========================================================================
// 256x256 8-phase bf16 GEMM (scores): C = alpha * A @ Bt^T, K multiple of 64,
// grid (N/256, M/256, batch), 512 threads = 8 waves (2M x 4N), BK=64.
// Counted vmcnt(8), raw s_barrier, T2 XOR-swizzle, T5 setprio. nt >= 3.
// ===========================================================================
__global__ __launch_bounds__(512) void gemm256_bt_scale(
    const bf16_t* __restrict__ A, long aBatch, int lda,
    const bf16_t* __restrict__ Bt, long bBatch, int ldb,
    float* __restrict__ C, long cBatch, int ldc,
    float alpha, int K)
{
  extern __shared__ char smem[];
  typedef __attribute__((address_space(3))) char lds_char_t;
  const unsigned ldsBase = (unsigned)(size_t)(lds_char_t*)smem;

  const unsigned gx = gridDim.x, gy = gridDim.y;
  const unsigned nwg = gx * gy * gridDim.z;
  const unsigned lin = blockIdx.x + gx * (blockIdx.y + gy * blockIdx.z);
  const unsigned swz = (lin & 7u) * (nwg >> 3) + (lin >> 3);
  const unsigned bx = swz % gx;
  const unsigned tq = swz / gx;
  const unsigned by = tq % gy;
  const unsigned bz = tq / gy;

  A += (long)bz * aBatch;
  Bt += (long)bz * bBatch;
  C += (long)bz * cBatch;

  const int tid = threadIdx.x, wid = tid >> 6, lane = tid & 63;
  const int wm = wid >> 2, wn = wid & 3;     // 2M x 4N waves; per-wave out 128x64
  const int lr = lane & 15, lh = lane >> 4;
  const int sw2 = ((lr >> 3) & 1) << 1;
  const unsigned cbyte = (unsigned)((lh ^ sw2) << 4);

  const int gsw = ((lane >> 5) & 1) << 1;
  const int gcol = ((lane & 3) ^ gsw) << 3;
  const int grow = wid * 16 + (lane >> 2);
  const bf16_t* Ag = A + (long)(by * 256 + grow) * lda + gcol;
  const bf16_t* Bg = Bt + (long)(bx * 256 + grow) * ldb + gcol;

#define STAGE_A(KT, H, B_) do { \
    const bf16_t* _s = Ag + (long)(KT) * 64 + (H) * 32; \
    bf16_t* _d = (bf16_t*)(smem + (B_) * 32768 + (H) * 16384 + wid * 1024); \
    gload_lds16(_s, _d); \
    gload_lds16(_s + (long)128 * lda, (bf16_t*)((char*)_d + 8192)); \
  } while (0)
#define STAGE_B(KT, H, B_) do { \
    const bf16_t* _s = Bg + (long)(KT) * 64 + (H) * 32; \
    bf16_t* _d = (bf16_t*)(smem + 65536 + (B_) * 32768 + (H) * 16384 + wid * 1024); \
    gload_lds16(_s, _d); \
    gload_lds16(_s + (long)128 * ldb, (bf16_t*)((char*)_d + 8192)); \
  } while (0)

  const unsigned aAddr = ldsBase + (unsigned)((wm * 128 + lr) * 64) + cbyte;
  const unsigned bAddr = ldsBase + 65536u + (unsigned)((wn * 64 + lr) * 64) + cbyte;

  bf16x8_t aF[4], bF[4];
  f32x4_t acc[8][4] = {};

#define MFMA16(MH) do { \
    __builtin_amdgcn_s_setprio(1); \
    _Pragma("unroll") for (int _n = 0; _n < 4; ++_n) \
      _Pragma("unroll") for (int _m = 0; _m < 4; ++_m) \
        acc[(MH) * 4 + _m][_n] = __builtin_amdgcn_mfma_f32_16x16x32_bf16( \
            aF[_m], bF[_n], acc[(MH) * 4 + _m][_n], 0, 0, 0); \
    __builtin_amdgcn_s_setprio(0); \
  } while (0)

#define PHASE(MH, H, B_, STAGE_STMT, VM_STMT) do { \
    _Pragma("unroll") for (int _m = 0; _m < 4; ++_m) \
      aF[_m] = ds_read_b128_bf16(aAddr + (unsigned)(B_)*32768u + (H)*16384u + ((MH)*4 + _m)*1024u); \
    if ((MH) == 0) { \
      _Pragma("unroll") for (int _n = 0; _n < 4; ++_n) \
        bF[_n] = ds_read_b128_bf16(bAddr + (unsigned)(B_)*32768u + (H)*16384u + _n*1024u); \
    } \
    STAGE_STMT; \
    VM_STMT; \
    __builtin_amdgcn_s_barrier(); \
    WAIT_LGKM0; \
    SCHED_FENCE; \
    MFMA16(MH); \
    __builtin_amdgcn_s_barrier(); \
    SCHED_FENCE; \
  } while (0)

  const int nt = K >> 6;  // >= 3

  STAGE_A(0, 0, 0); STAGE_B(0, 0, 0); STAGE_A(0, 1, 0); STAGE_B(0, 1, 0);
  STAGE_A(1, 0, 1); STAGE_B(1, 0, 1);
  WAIT_VM(8);
  __builtin_amdgcn_s_barrier();
  SCHED_FENCE;

  int bufc = 0;
  for (int kt = 0; kt < nt; ++kt, bufc ^= 1) {
    const int bo = bufc ^ 1;
    const bool st12 = (kt + 1 < nt);
    const bool st34 = (kt + 2 < nt);
    PHASE(0, 0, bufc, if (st12) STAGE_A(kt + 1, 1, bo), );
    PHASE(1, 0, bufc, if (st12) STAGE_B(kt + 1, 1, bo),
          if (kt == nt - 1) { WAIT_VM(0); } else { WAIT_VM(8); });
    PHASE(0, 1, bufc, if (st34) STAGE_A(kt + 2, 0, bufc), );
    PHASE(1, 1, bufc, if (st34) STAGE_B(kt + 2, 0, bufc),
          if (kt < nt - 2) { WAIT_VM(8); } else { WAIT_VM(4); });
  }

  const long r0 = (long)by * 256 + wm * 128;
  const int c0 = bx * 256 + wn * 64;
#pragma unroll
  for (int m = 0; m < 8; ++m)
#pragma unroll
    for (int n = 0; n < 4; ++n)
#pragma unroll
      for (int r = 0; r < 4; ++r)
        C[(r0 + m * 16 + lh * 4 + r) * ldc + c0 + n * 16 + lr] = acc[m][n][r] * alpha;

#undef PHASE
#undef MFMA16
#undef STAGE_A
#undef STAGE_B
}

// ===========================================================================
// 256x128 8-phase bf16 GEMM for PV / FFN / proj: C = epi(A @ Bt^T), BK=64.
// grid (N/128, M/256, batch) — 256 wgs for all our shapes. 512 threads =
// 8 waves (4M x 2N), per-wave out 64x64. LDS 96 KiB dynamic:
// A ring 4x16 KiB chunks (256x32), B ring 4x8 KiB chunks (128x32).
// One chunk (3 issues: A2+B1) staged per phase -> counted vmcnt(6).
// Requires nt = K/64 >= 3.
// ===========================================================================
template <int EPI>
__global__ __launch_bounds__(512) void gemm256x128_bt(
    const bf16_t* __restrict__ A, long aBatch, int lda,
    const bf16_t* __restrict__ Bt, long bBatch, int ldb,
    float* __restrict__ Cf, long cfBatch, int ldc,
    bf16_t* __restrict__ Cb, long cbBatch,
    const float* __restrict__ Res, long resBatch,
    const float* __restrict__ bias, int K)
{
  extern __shared__ char smem[];
  typedef __attribute__((address_space(3))) char lds_char_t;
  const unsigned ldsBase = (unsigned)(size_t)(lds_char_t*)smem;

  const unsigned gx = gridDim.x, gy = gridDim.y;
  const unsigned nwg = gx * gy * gridDim.z;
  const unsigned lin = blockIdx.x + gx * (blockIdx.y + gy * blockIdx.z);
  const unsigned swz = (lin & 7u) * (nwg >> 3) + (lin >> 3);
  const unsigned bx = swz % gx;
  const unsigned tq = swz / gx;
  const unsigned by = tq % gy;
  const unsigned bz = tq / gy;

  A += (long)bz * aBatch;
  Bt += (long)bz * bBatch;
  Cf += (long)bz * cfBatch;
  if (Cb) Cb += (long)bz * cbBatch;
  if (Res) Res += (long)bz * resBatch;

  const int tid = threadIdx.x, wid = tid >> 6, lane = tid & 63;
  const int wm = wid >> 1, wn = wid & 1;     // 4M x 2N waves; per-wave out 64x64
  const int lr = lane & 15, lh = lane >> 4;
  const int sw2 = ((lr >> 3) & 1) << 1;
  const unsigned cbyte = (unsigned)((lh ^ sw2) << 4);

  // staging: thread covers row wid*16 + lane/4 (+128 for A's 2nd issue),
  // source col pre-swizzled by row bit3 (= lane bit5)
  const int gsw = ((lane >> 5) & 1) << 1;
  const int gcol = ((lane & 3) ^ gsw) << 3;
  const int grow = wid * 16 + (lane >> 2);
  const bf16_t* Ag = A + (long)(by * 256 + grow) * lda + gcol;
  const bf16_t* Bg = Bt + (long)(bx * 128 + grow) * ldb + gcol;

  // LDS arena: A chunks at b*32768 + h*16384 (16 KiB each);
  //            B chunks at 65536 + b*16384 + h*8192 (8 KiB each). Total 96 KiB.
#define STAGE_A2(KT, H, B_) do { \
    const bf16_t* _s = Ag + (long)(KT) * 64 + (H) * 32; \
    bf16_t* _d = (bf16_t*)(smem + (B_) * 32768 + (H) * 16384 + wid * 1024); \
    gload_lds16(_s, _d); \
    gload_lds16(_s + (long)128 * lda, (bf16_t*)((char*)_d + 8192)); \
  } while (0)
#define STAGE_B1(KT, H, B_) do { \
    const bf16_t* _s = Bg + (long)(KT) * 64 + (H) * 32; \
    bf16_t* _d = (bf16_t*)(smem + 65536 + (B_) * 16384 + (H) * 8192 + wid * 1024); \
    gload_lds16(_s, _d); \
  } while (0)

  const unsigned aAddr = ldsBase + (unsigned)((wm * 64 + lr) * 64) + cbyte;
  const unsigned bAddr = ldsBase + 65536u + (unsigned)((wn * 64 + lr) * 64) + cbyte;

  bf16x8_t aF[4], bF[4];
  f32x4_t acc[4][4] = {};

  // phase: ds_read A(4)+B(4) -> stage next chunk -> vm wait -> barrier ->
  //        lgkm0 -> 16 MFMA -> barrier
#define PHASE(H, B_, STAGE_STMT, VM_STMT) do { \
    _Pragma("unroll") for (int _m = 0; _m < 4; ++_m) \
      aF[_m] = ds_read_b128_bf16(aAddr + (unsigned)(B_)*32768u + (H)*16384u + _m*1024u); \
    _Pragma("unroll") for (int _n = 0; _n < 4; ++_n) \
      bF[_n] = ds_read_b128_bf16(bAddr + (unsigned)(B_)*16384u + (H)*8192u + _n*1024u); \
    STAGE_STMT; \
    VM_STMT; \
    __builtin_amdgcn_s_barrier(); \
    WAIT_LGKM0; \
    SCHED_FENCE; \
    __builtin_amdgcn_s_setprio(1); \
    _Pragma("unroll") for (int _n = 0; _n < 4; ++_n) \
      _Pragma("unroll") for (int _m = 0; _m < 4; ++_m) \
        acc[_m][_n] = __builtin_amdgcn_mfma_f32_16x16x32_bf16(aF[_m], bF[_n], acc[_m][_n], 0, 0, 0); \
    __builtin_amdgcn_s_setprio(0); \
    __builtin_amdgcn_s_barrier(); \
    SCHED_FENCE; \
  } while (0)

  const int nt = K >> 6;  // >= 3

  // prologue: chunks (0,h0), (0,h1), (1,h0); wait oldest 3 -> vmcnt(6)
  STAGE_A2(0, 0, 0); STAGE_B1(0, 0, 0);
  STAGE_A2(0, 1, 0); STAGE_B1(0, 1, 0);
  STAGE_A2(1, 0, 1); STAGE_B1(1, 0, 1);
  WAIT_VM(6);
  __builtin_amdgcn_s_barrier();
  SCHED_FENCE;

  int bufc = 0;
  for (int kt = 0; kt < nt; ++kt, bufc ^= 1) {
    const int bo = bufc ^ 1;
    PHASE(0, bufc,
          if (kt + 1 < nt) { STAGE_A2(kt + 1, 1, bo); STAGE_B1(kt + 1, 1, bo); },
          if (kt + 1 < nt) { WAIT_VM(6); } else { WAIT_VM(0); });
    PHASE(1, bufc,
          if (kt + 2 < nt) { STAGE_A2(kt + 2, 0, bufc); STAGE_B1(kt + 2, 0, bufc); },
          if (kt + 2 < nt) { WAIT_VM(6); } else if (kt + 1 < nt) { WAIT_VM(3); });
  }

  // epilogue: C/D layout col = lane&15, row = (lane>>4)*4 + reg
  const long r0 = (long)by * 256 + wm * 64;
  const int c0 = bx * 128 + wn * 64;
#pragma unroll
  for (int m = 0; m < 4; ++m) {
#pragma unroll
    for (int n = 0; n < 4; ++n) {
#pragma unroll
      for (int r = 0; r < 4; ++r) {
        const long row = r0 + m * 16 + lh * 4 + r;
        const int col = c0 + n * 16 + lr;
        const float v = acc[m][n][r];
        if constexpr (EPI == EPI_BIAS) {
          Cf[row * ldc + col] = v + bias[col];
        } else if constexpr (EPI == EPI_RES_BF16) {
          const float o = Res[row * ldc + col] + v;
          Cf[row * ldc + col] = o;
          Cb[row * ldc + col] = (bf16_t)o;
        } else {  // EPI_RELU_RES
          float t = v + bias[col];
          t = t > 0.f ? t : 0.f;
          const float o = Res[row * ldc + col] + t;
          Cf[row * ldc + col] = o;
          Cb[row * ldc + col] = (bf16_t)o;
        }
      }
    }
  }
#undef PHASE
#undef STAGE_A2
#undef STAGE_B1
}

// ---------------------------------------------------------------------------
// Row softmax over S f32 values, in-place bf16 writeback (rows at f32 stride,
// so P is later read with lda = 2*S bf16 elems). One block (256 thr) per row.
// ---------------------------------------------------------------------------
__global__ __launch_bounds__(256) void softmax_rows(float* __restrict__ scores, int S)
{
  const long row = blockIdx.x;
  float* p = scores + row * (long)S;
  const int t = threadIdx.x;
  const int lane = t & 63, wave = t >> 6;

  float4 v0 = ((const float4*)p)[t * 2];
  float4 v1 = ((const float4*)p)[t * 2 + 1];
  float e[8] = {v0.x, v0.y, v0.z, v0.w, v1.x, v1.y, v1.z, v1.w};

  float m = e[0];
#pragma unroll
  for (int j = 1; j < 8; ++j) m = fmaxf(m, e[j]);
#pragma unroll
  for (int off = 32; off >= 1; off >>= 1) m = fmaxf(m, __shfl_xor(m, off));

  __shared__ float redm[4], reds[4];
  if (lane == 0) redm[wave] = m;
  __syncthreads();
  m = fmaxf(fmaxf(redm[0], redm[1]), fmaxf(redm[2], redm[3]));

  float s = 0.f;
#pragma unroll
  for (int j = 0; j < 8; ++j) { e[j] = __expf(e[j] - m); s += e[j]; }
#pragma unroll
  for (int off = 32; off >= 1; off >>= 1) s += __shfl_xor(s, off);
  if (lane == 0) reds[wave] = s;
  __syncthreads();
  s = reds[0] + reds[1] + reds[2] + reds[3];
  const float inv = 1.f / s;

  bf16x8_t ob;
#pragma unroll
  for (int j = 0; j < 8; ++j) ob[j] = (bf16_t)(e[j] * inv);
  ((bf16x8_t*)p)[t] = ob;
}

// ---------------------------------------------------------------------------
__global__ void cast_copy(const float* __restrict__ in, float* __restrict__ outf,
                          bf16_t* __restrict__ outb, long n4)
{
  long i = (long)blockIdx.x * blockDim.x + threadIdx.x;
  const long stride = (long)gridDim.x * blockDim.x;
  for (; i < n4; i += stride) {
    float4 v = ((const float4*)in)[i];
    ((float4*)outf)[i] = v;
    bf16x4_t bv;
    bv[0] = (bf16_t)v.x; bv[1] = (bf16_t)v.y; bv[2] = (bf16_t)v.z; bv[3] = (bf16_t)v.w;
    ((bf16x4_t*)outb)[i] = bv;
  }
}

// ---------------------------------------------------------------------------
__global__ void transpose_cast(const float* __restrict__ in, long inBatch, int R, int C,
                               bf16_t* __restrict__ out, long outBatch)
{
  __shared__ float tile[32][33];
  const float* src = in + (long)blockIdx.z * inBatch;
  bf16_t* dst = out + (long)blockIdx.z * outBatch;
  const int c0 = blockIdx.x * 32, r0 = blockIdx.y * 32;
  const int tx = threadIdx.x, ty = threadIdx.y;
#pragma unroll
  for (int i = 0; i < 32; i += 8) tile[ty + i][tx] = src[(long)(r0 + ty + i) * C + (c0 + tx)];
  __syncthreads();
#pragma unroll
  for (int i = 0; i < 32; i += 8)
    dst[(long)(c0 + ty + i) * R + (r0 + tx)] = (bf16_t)tile[tx][ty + i];
}

// ---------------------------------------------------------------------------
extern "C" void kernel_launch(void* const* d_in, const int* in_sizes, int n_in,
                              void* d_out, int out_size, void* d_ws, size_t ws_size,
                              hipStream_t stream)
{
  constexpr int L = 4, NB = 4, S = 2048, D = 1024;
  const float* x  = (const float*)d_in[0];
  const float* W  = (const float*)d_in[1];
  const float* bv = (const float*)d_in[2];
  const float* Wo = (const float*)d_in[3];
  const float* bo = (const float*)d_in[4];

  char* ws = (char*)d_ws;
  size_t off = 0;
  float* scores = (float*)(ws + off); off += (size_t)NB * S * S * 4;
  float* xf = (float*)(ws + off); off += (size_t)NB * S * D * 4;
  float* yf = (float*)(ws + off); off += (size_t)NB * S * D * 4;
  bf16_t* xb  = (bf16_t*)(ws + off); off += (size_t)NB * S * D * 2;
  bf16_t* xbT = (bf16_t*)(ws + off); off += (size_t)NB * S * D * 2;
  bf16_t* yb  = (bf16_t*)(ws + off); off += (size_t)NB * S * D * 2;
  bf16_t* WbT  = (bf16_t*)(ws + off); off += (size_t)L * D * D * 2;
  bf16_t* WobT = (bf16_t*)(ws + off); off += (size_t)D * D * 2;

  hipFuncSetAttribute((const void*)gemm256_bt_scale,
                      hipFuncAttributeMaxDynamicSharedMemorySize, 131072);
  hipFuncSetAttribute((const void*)gemm256x128_bt<EPI_RES_BF16>,
                      hipFuncAttributeMaxDynamicSharedMemorySize, 98304);
  hipFuncSetAttribute((const void*)gemm256x128_bt<EPI_RELU_RES>,
                      hipFuncAttributeMaxDynamicSharedMemorySize, 98304);
  hipFuncSetAttribute((const void*)gemm256x128_bt<EPI_BIAS>,
                      hipFuncAttributeMaxDynamicSharedMemorySize, 98304);

  const long n4 = (long)NB * S * D / 4;
  cast_copy<<<2048, 256, 0, stream>>>(x, xf, xb, n4);
  transpose_cast<<<dim3(D / 32, S / 32, NB), dim3(32, 8), 0, stream>>>(
      x, (long)S * D, S, D, xbT, (long)D * S);
  transpose_cast<<<dim3(D / 32, D / 32, L), dim3(32, 8), 0, stream>>>(
      W, (long)D * D, D, D, WbT, (long)D * D);
  transpose_cast<<<dim3(D / 32, D / 32, 1), dim3(32, 8), 0, stream>>>(
      Wo, 0, D, D, WobT, 0);

  const float inv_sqrt_d = 0.03125f;  // 1/sqrt(1024)

  for (int i = 0; i < L; ++i) {
    // scores = xb @ xb^T * inv_sqrt_d  (256^2 8-phase kernel)
    gemm256_bt_scale<<<dim3(S / 256, S / 256, NB), 512, 131072, stream>>>(
        xb, (long)S * D, D, xb, (long)S * D, D,
        scores, (long)S * S, S, inv_sqrt_d, D);
    // softmax rows, in-place bf16 P (lda = 2*S)
    softmax_rows<<<NB * S, 256, 0, stream>>>(scores, S);
    // y = xf + P @ x   (Bt = xbT)  — 256x128 8-phase, grid 256 wgs
    gemm256x128_bt<EPI_RES_BF16><<<dim3(D / 128, S / 256, NB), 512, 98304, stream>>>(
        (const bf16_t*)scores, (long)2 * S * S, 2 * S, xbT, (long)D * S, S,
        yf, (long)S * D, D, yb, (long)S * D, xf, (long)S * D, nullptr, S);
    // z = yf + relu(yb @ W[i] + b[i])  -> xf, xb
    gemm256x128_bt<EPI_RELU_RES><<<dim3(D / 128, (NB * S) / 256, 1), 512, 98304, stream>>>(
        yb, 0, D, WbT + (size_t)i * D * D, 0, D,
        xf, 0, D, xb, 0, yf, 0, bv + (size_t)i * D, D);
    if (i < L - 1)
      transpose_cast<<<dim3(D / 32, S / 32, NB), dim3(32, 8), 0, stream>>>(
          xf, (long)S * D, S, D, xbT, (long)D * S);
  }

  // out = xb @ Wo + bo
  gemm256x128_bt<EPI_BIAS><<<dim3(D / 128, (NB * S) / 256, 1), 512, 98304, stream>>>(
      xb, 0, D, WobT, 0, D,
      (float*)d_out, 0, D, nullptr, 0, nullptr, 0, bo, D);
}